// Round 33
// baseline (39.712 us; speedup 1.0000x reference)
//
#include <hip/hip_runtime.h>
#include <hip/hip_fp8.h>

// R33 = R29 (36.45us verified best) + wide macro-loads WITHOUT shuffles.
// Key insight: M/Dt column assignment is an arbitrary fixed permutation
// (A,B share it; MFMA is column-permutation-invariant — the eperm property
// verified in R13/R28). So sub-matrix j of a 256-edge macro holds edge 4l+j
// in column eperm(l): lane l loads 4 CONSECUTIVE edges via float4/int4
// (6 wide VMEM per 256 edges vs 24 narrow) and runs 4 sub-group bodies from
// registers. R15's regression was its 20-shfl redistribution - eliminated.
// Sub-group body / search / fp8 layout / reduce tree byte-identical to R29.

#define NG 64
#define NCOMP 6
#define NPART (NG * NCOMP)      // 384
#define RED1_BLOCKS 64
#define MFMA_BLOCKS 1024        // 4 blocks/CU
#define WPB 4
#define MROWB 80                // 64 + 16 pad bytes; 16B-aligned rows
#define DROWB 80
#define DTROWS 6                // rows 0..5 real; C cols 6..15 discarded

typedef unsigned char  u8_t;
typedef unsigned int   u32_t;
typedef __attribute__((ext_vector_type(2))) long long long2_t;
typedef __attribute__((ext_vector_type(4))) float f32x4;

__device__ __forceinline__ int eperm(int e) {
    return (((e >> 3) & 3) << 4) | (((e >> 5) & 1) << 3) | (e & 7);
}

__device__ __forceinline__ u8_t f2fp8(float f) {
    return (u8_t)__hip_cvt_float_to_fp8(f, __HIP_SATFINITE, __HIP_E4M3);
}

__device__ __forceinline__ void lds_add(float* p, float v) {
    __hip_atomic_fetch_add(p, v, __ATOMIC_RELAXED, __HIP_MEMORY_SCOPE_WORKGROUP);
}

// Estimate-and-verify: g = max{g : Bs[g] <= a}. Bs[0]=0, Bs[64]=N sentinel.
__device__ __forceinline__ int gsearch(const int* Bs, int a, float rcpN) {
    int g = (int)((float)a * rcpN);
    g = g > 63 ? 63 : g;
    while (Bs[g] > a) --g;          // fires for ~4% of lanes
    while (Bs[g + 1] <= a) ++g;     // fires for ~4% of lanes
    return g;
}

// ---------------- MFMA main kernel (fp8, wide macro-loads) ----------------
__global__ __launch_bounds__(256) void virial_mfma(
    const float* __restrict__ disp, const float* __restrict__ edge_w,
    const int* __restrict__ edge_index, const int* __restrict__ batch,
    float* __restrict__ partials, int E, int N, float rcpN)
{
    __shared__ u8_t Msh[WPB][NG * MROWB];       // 4 x 5120 B (reused as f32 stage)
    __shared__ u8_t Dsh[WPB][DTROWS * DROWB];   // 4 x  480 B
    __shared__ int  Bs[65];                     //   260 B

    const int lane = threadIdx.x & 63;
    const int wave = threadIdx.x >> 6;
    u8_t* Mw = Msh[wave];
    u8_t* Dw = Dsh[wave];

    // Fused bounds table: Bs[g] = lower_bound(batch, g) (batch sorted, L2-hot)
    if (threadIdx.x < 65) {
        int g = threadIdx.x;
        int lo = 0, len = N;
        while (len > 0) {
            int half = len >> 1;
            int mid  = lo + half;
            if (batch[mid] < g) { lo = mid + 1; len -= half + 1; }
            else                { len = half; }
        }
        Bs[g] = lo;    // g=64 -> N (sentinel)
    }
    {   // zero per-wave M and Dt (same-wave DS ops are in order)
        u32_t* p = (u32_t*)Mw;
        for (int i = lane; i < NG * MROWB / 4; i += 64) p[i] = 0u;
        u32_t* q = (u32_t*)Dw;
        for (int i = lane; i < DTROWS * DROWB / 4; i += 64) q[i] = 0u;
    }
    __syncthreads();   // Bs ready

    f32x4 acc0 = {0,0,0,0}, acc1 = {0,0,0,0}, acc2 = {0,0,0,0}, acc3 = {0,0,0,0};
    const int nmacros = (E + 255) >> 8;
    const int mstride = (int)gridDim.x * WPB;
    const int c_l  = lane & 15;
    const int k4   = lane >> 4;
    const int mcol = eperm(lane);                            // storage column
    const int drow = (c_l < DTROWS) ? c_l : (DTROWS - 1);    // junk -> discarded C cols
    int pg0 = 0, pg1 = 0;

    // Load one 256-edge macro: lane holds 4 consecutive edges (eb = mac*256+4*lane)
#define LOADM(MAC, W4, DA, DB, DC, S4, T4) do {                               \
        int eb_ = (MAC) * 256 + 4 * lane;                                     \
        if (((MAC) + 1) * 256 <= E) {                                         \
            W4 = *(const float4*)&edge_w[eb_];                                \
            DA = *(const float4*)&disp[eb_ * 3 + 0];                          \
            DB = *(const float4*)&disp[eb_ * 3 + 4];                          \
            DC = *(const float4*)&disp[eb_ * 3 + 8];                          \
            S4 = *(const int4*)&edge_index[eb_];                              \
            T4 = *(const int4*)&edge_index[E + eb_];                          \
        } else {                                                              \
            float w_[4], x_[12]; int s_[4], t_[4];                            \
            _Pragma("unroll")                                                 \
            for (int k_ = 0; k_ < 4; ++k_) {                                  \
                int e_  = eb_ + k_;                                           \
                int ec_ = e_ < E ? e_ : E - 1;                                \
                w_[k_] = (e_ < E) ? edge_w[ec_] : 0.f;                        \
                x_[3*k_+0] = disp[ec_*3+0];                                   \
                x_[3*k_+1] = disp[ec_*3+1];                                   \
                x_[3*k_+2] = disp[ec_*3+2];                                   \
                s_[k_] = edge_index[ec_];                                     \
                t_[k_] = edge_index[E + ec_];                                 \
            }                                                                 \
            W4 = make_float4(w_[0], w_[1], w_[2], w_[3]);                     \
            DA = make_float4(x_[0], x_[1], x_[2],  x_[3]);                    \
            DB = make_float4(x_[4], x_[5], x_[6],  x_[7]);                    \
            DC = make_float4(x_[8], x_[9], x_[10], x_[11]);                   \
            S4 = make_int4(s_[0], s_[1], s_[2], s_[3]);                       \
            T4 = make_int4(t_[0], t_[1], t_[2], t_[3]);                       \
        }                                                                     \
    } while (0)

    // R29-verified per-sub-group body (edge 4l+j in column mcol)
#define SUBG(W, X, Y, Z, S, T) do {                                           \
        const int g0_ = gsearch(Bs, S, rcpN);                                 \
        const int g1_ = gsearch(Bs, T, rcpN);                                 \
        Mw[pg0 * MROWB + mcol] = 0;                                           \
        Mw[pg1 * MROWB + mcol] = 0;                                           \
        Mw[g0_ * MROWB + mcol] = 0x38u;                                       \
        Mw[g1_ * MROWB + mcol] = (g1_ == g0_) ? 0x40u : 0x38u;                \
        pg0 = g0_; pg1 = g1_;                                                 \
        float cw_ = -2.f * W;                                                 \
        Dw[0 * DROWB + mcol] = f2fp8(cw_ * X * X);                            \
        Dw[1 * DROWB + mcol] = f2fp8(cw_ * X * Y);                            \
        Dw[2 * DROWB + mcol] = f2fp8(cw_ * X * Z);                            \
        Dw[3 * DROWB + mcol] = f2fp8(cw_ * Y * Y);                            \
        Dw[4 * DROWB + mcol] = f2fp8(cw_ * Y * Z);                            \
        Dw[5 * DROWB + mcol] = f2fp8(cw_ * Z * Z);                            \
        long2_t bf_ = *(const long2_t*)&Dw[drow * DROWB + k4 * 16];           \
        long2_t a0_ = *(const long2_t*)&Mw[( 0 + c_l) * MROWB + k4 * 16];     \
        long2_t a1_ = *(const long2_t*)&Mw[(16 + c_l) * MROWB + k4 * 16];     \
        long2_t a2_ = *(const long2_t*)&Mw[(32 + c_l) * MROWB + k4 * 16];     \
        long2_t a3_ = *(const long2_t*)&Mw[(48 + c_l) * MROWB + k4 * 16];     \
        acc0 = __builtin_amdgcn_mfma_f32_16x16x32_fp8_fp8(a0_[0], bf_[0], acc0, 0, 0, 0); \
        acc1 = __builtin_amdgcn_mfma_f32_16x16x32_fp8_fp8(a1_[0], bf_[0], acc1, 0, 0, 0); \
        acc2 = __builtin_amdgcn_mfma_f32_16x16x32_fp8_fp8(a2_[0], bf_[0], acc2, 0, 0, 0); \
        acc3 = __builtin_amdgcn_mfma_f32_16x16x32_fp8_fp8(a3_[0], bf_[0], acc3, 0, 0, 0); \
        acc0 = __builtin_amdgcn_mfma_f32_16x16x32_fp8_fp8(a0_[1], bf_[1], acc0, 0, 0, 0); \
        acc1 = __builtin_amdgcn_mfma_f32_16x16x32_fp8_fp8(a1_[1], bf_[1], acc1, 0, 0, 0); \
        acc2 = __builtin_amdgcn_mfma_f32_16x16x32_fp8_fp8(a2_[1], bf_[1], acc2, 0, 0, 0); \
        acc3 = __builtin_amdgcn_mfma_f32_16x16x32_fp8_fp8(a3_[1], bf_[1], acc3, 0, 0, 0); \
    } while (0)

    int mac = (int)blockIdx.x * WPB + wave;

    // 1-deep macro prefetch
    float4 nw4 = {0,0,0,0}, ndA = {0,0,0,0}, ndB = {0,0,0,0}, ndC = {0,0,0,0};
    int4   ns4 = {0,0,0,0}, nt4 = {0,0,0,0};
    if (mac < nmacros) LOADM(mac, nw4, ndA, ndB, ndC, ns4, nt4);

    while (mac < nmacros) {
        const float4 w4 = nw4, dA = ndA, dB = ndB, dC = ndC;
        const int4   s4 = ns4, t4 = nt4;
        const int nxt = mac + mstride;
        if (nxt < nmacros) LOADM(nxt, nw4, ndA, ndB, ndC, ns4, nt4);

        // 4 sub-groups; edge 4l+j's disp = elems 3j..3j+2 of lane's 12 floats
        SUBG(w4.x, dA.x, dA.y, dA.z, s4.x, t4.x);
        SUBG(w4.y, dA.w, dB.x, dB.y, s4.y, t4.y);
        SUBG(w4.z, dB.z, dB.w, dC.x, s4.z, t4.z);
        SUBG(w4.w, dC.y, dC.z, dC.w, s4.w, t4.w);

        mac = nxt;
    }
#undef LOADM
#undef SUBG

    // C/D layout: col=lane&15, row=(lane>>4)*4+reg (dtype-independent).
    // Stage per-wave f32 partial into this wave's (now dead) M region.
    __syncthreads();
    float* Ow = (float*)Mw;   // 5120 B >= 1536 B needed
    if (c_l < NCOMP) {
#pragma unroll
        for (int r = 0; r < 4; ++r) {
            Ow[( 0 + k4 * 4 + r) * NCOMP + c_l] = acc0[r];
            Ow[(16 + k4 * 4 + r) * NCOMP + c_l] = acc1[r];
            Ow[(32 + k4 * 4 + r) * NCOMP + c_l] = acc2[r];
            Ow[(48 + k4 * 4 + r) * NCOMP + c_l] = acc3[r];
        }
    }
    __syncthreads();
    for (int i = threadIdx.x; i < NPART; i += blockDim.x) {
        float s = ((const float*)Msh[0])[i] + ((const float*)Msh[1])[i]
                + ((const float*)Msh[2])[i] + ((const float*)Msh[3])[i];
        partials[(size_t)blockIdx.x * NPART + i] = s;
    }
}

// ---------------- reductions (atomic-free; R22-verified) ----------------
__global__ __launch_bounds__(NPART) void reduce1_kernel(
    const float* __restrict__ partials, float* __restrict__ partials2, int nblk)
{
    int i = threadIdx.x, j = blockIdx.x;
    float s = 0.f;
    for (int b = j; b < nblk; b += RED1_BLOCKS)
        s += partials[(size_t)b * NPART + i];
    partials2[(size_t)j * NPART + i] = s;
}

__global__ __launch_bounds__(NPART) void reduce2_kernel(
    const float* __restrict__ partials2, float* __restrict__ dst)  // dst: 64*9
{
    int i = threadIdx.x;
    float s = 0.f;
#pragma unroll
    for (int j = 0; j < RED1_BLOCKS; ++j)
        s += partials2[(size_t)j * NPART + i];
    int g = i / NCOMP, c = i % NCOMP;
    int r   = (c < 3) ? 0 : ((c < 5) ? 1 : 2);
    int col = (c < 3) ? c : ((c < 5) ? c - 2 : 2);
    dst[g * 9 + r * 3 + col] = s;
    if (r != col) dst[g * 9 + col * 3 + r] = s;
}

// ---------------- fallback (tiny ws): LDS-atomic path ----------------
__global__ void zero_out_kernel(float* __restrict__ out, int n) {
    int i = blockIdx.x * blockDim.x + threadIdx.x;
    if (i < n) out[i] = 0.f;
}

__global__ __launch_bounds__(256) void virial_atomic(
    const float* __restrict__ disp, const float* __restrict__ edge_w,
    const int* __restrict__ edge_index, const int* __restrict__ batch,
    float* __restrict__ out, int E)
{
    __shared__ float acc[NG * 7];
    for (int i = threadIdx.x; i < NG * 7; i += blockDim.x) acc[i] = 0.f;
    __syncthreads();
    int tid = blockIdx.x * blockDim.x + threadIdx.x;
    int stride = gridDim.x * blockDim.x;
    for (int e = tid; e < E; e += stride) {
        float d0 = disp[e*3], d1 = disp[e*3+1], d2 = disp[e*3+2];
        float c = -2.f * edge_w[e];
        int g0 = batch[edge_index[e]], g1 = batch[edge_index[E + e]];
        float v[6] = {c*d0*d0, c*d0*d1, c*d0*d2, c*d1*d1, c*d1*d2, c*d2*d2};
#pragma unroll
        for (int k = 0; k < 6; ++k) {
            lds_add(&acc[g0*7+k], v[k]);
            lds_add(&acc[g1*7+k], v[k]);
        }
    }
    __syncthreads();
    for (int i = threadIdx.x; i < NG * 9; i += blockDim.x) {
        int g = i / 9, ij = i % 9, r = ij / 3, cc = ij % 3;
        int lo = r < cc ? r : cc, hi = r < cc ? cc : r;
        int comp = (lo == 0) ? hi : ((lo == 1) ? 2 + hi : 5);
        __hip_atomic_fetch_add(&out[i], acc[g*7+comp], __ATOMIC_RELAXED, __HIP_MEMORY_SCOPE_AGENT);
    }
}

extern "C" void kernel_launch(void* const* d_in, const int* in_sizes, int n_in,
                              void* d_out, int out_size, void* d_ws, size_t ws_size,
                              hipStream_t stream) {
    const float* disp       = (const float*)d_in[0];
    const float* edge_w     = (const float*)d_in[1];
    const int*   edge_index = (const int*)d_in[2];
    const int*   batch      = (const int*)d_in[3];
    float*       out        = (float*)d_out;
    const int E = in_sizes[1];
    const int N = in_sizes[3];
    const float rcpN = (float)NG / (float)N;

    const size_t need = (size_t)(MFMA_BLOCKS + RED1_BLOCKS) * NPART * sizeof(float);

    if (ws_size >= need) {
        float* pm = (float*)d_ws;                         // [MFMA_BLOCKS][NPART]
        float* p2 = pm + (size_t)MFMA_BLOCKS * NPART;     // [RED1_BLOCKS][NPART]

        virial_mfma<<<MFMA_BLOCKS, 256, 0, stream>>>(disp, edge_w, edge_index,
                                                     batch, pm, E, N, rcpN);
        reduce1_kernel<<<RED1_BLOCKS, NPART, 0, stream>>>(pm, p2, MFMA_BLOCKS);
        reduce2_kernel<<<1, NPART, 0, stream>>>(p2, out);
    } else {
        zero_out_kernel<<<1, 256, 0, stream>>>(out, NG * 9);
        virial_atomic<<<2048, 256, 0, stream>>>(disp, edge_w, edge_index, batch, out, E);
    }
}

// Round 34
// 36.479 us; speedup vs baseline: 1.0886x; 1.0886x over previous
//
#include <hip/hip_runtime.h>
#include <hip/hip_fp8.h>

// FINAL (R29, verified 36.45us, absmax 512 vs threshold 2119).
// Ladder: 210us (LDS-atomic baseline) -> 44.2 (scatter-as-MFMA, no atomics)
// -> 39.8 (gather-free: batch is sorted -> 65-entry boundary table + search)
// -> 38.4 (fp8 e4m3 fragments, eperm interleave: 5 b128 reads/group)
// -> 36.45 (estimate-and-verify search + fused bounds build).
// Exhausted-neutral: occupancy both directions, 2-deep prefetch, LDS dbuf,
// wide VMEM loads, atomic epilogue (native but 590K adds on 576 addrs = +15us).

#define NG 64
#define NCOMP 6
#define NPART (NG * NCOMP)      // 384
#define RED1_BLOCKS 64
#define MFMA_BLOCKS 1024        // 4 blocks/CU
#define WPB 4
#define MROWB 80                // 64 + 16 pad bytes; 16B-aligned rows
#define DROWB 80
#define DTROWS 6                // rows 0..5 real; C cols 6..15 discarded

typedef unsigned char  u8_t;
typedef unsigned int   u32_t;
typedef __attribute__((ext_vector_type(2))) long long long2_t;
typedef __attribute__((ext_vector_type(4))) float f32x4;

__device__ __forceinline__ int eperm(int e) {
    return (((e >> 3) & 3) << 4) | (((e >> 5) & 1) << 3) | (e & 7);
}

__device__ __forceinline__ u8_t f2fp8(float f) {
    return (u8_t)__hip_cvt_float_to_fp8(f, __HIP_SATFINITE, __HIP_E4M3);
}

__device__ __forceinline__ void lds_add(float* p, float v) {
    __hip_atomic_fetch_add(p, v, __ATOMIC_RELAXED, __HIP_MEMORY_SCOPE_WORKGROUP);
}

// Estimate-and-verify: g = max{g : Bs[g] <= a}. Bs[0]=0, Bs[64]=N sentinel.
__device__ __forceinline__ int gsearch(const int* Bs, int a, float rcpN) {
    int g = (int)((float)a * rcpN);
    g = g > 63 ? 63 : g;
    while (Bs[g] > a) --g;          // fires for ~4% of lanes
    while (Bs[g + 1] <= a) ++g;     // fires for ~4% of lanes
    return g;
}

// ---------------- MFMA main kernel (fp8 fragments, fused bounds) ----------------
__global__ __launch_bounds__(256) void virial_mfma(
    const float* __restrict__ disp, const float* __restrict__ edge_w,
    const int* __restrict__ edge_index, const int* __restrict__ batch,
    float* __restrict__ partials, int E, int N, float rcpN)
{
    __shared__ u8_t Msh[WPB][NG * MROWB];       // 4 x 5120 B (reused as f32 stage)
    __shared__ u8_t Dsh[WPB][DTROWS * DROWB];   // 4 x  480 B
    __shared__ int  Bs[65];                     //   260 B

    const int lane = threadIdx.x & 63;
    const int wave = threadIdx.x >> 6;
    u8_t* Mw = Msh[wave];
    u8_t* Dw = Dsh[wave];

    // Fused bounds table: Bs[g] = lower_bound(batch, g) (batch sorted, L2-hot)
    if (threadIdx.x < 65) {
        int g = threadIdx.x;
        int lo = 0, len = N;
        while (len > 0) {
            int half = len >> 1;
            int mid  = lo + half;
            if (batch[mid] < g) { lo = mid + 1; len -= half + 1; }
            else                { len = half; }
        }
        Bs[g] = lo;    // g=64 -> N (sentinel)
    }
    {   // zero per-wave M and Dt (same-wave DS ops are in order)
        u32_t* p = (u32_t*)Mw;
        for (int i = lane; i < NG * MROWB / 4; i += 64) p[i] = 0u;
        u32_t* q = (u32_t*)Dw;
        for (int i = lane; i < DTROWS * DROWB / 4; i += 64) q[i] = 0u;
    }
    __syncthreads();   // Bs ready

    f32x4 acc0 = {0,0,0,0}, acc1 = {0,0,0,0}, acc2 = {0,0,0,0}, acc3 = {0,0,0,0};
    const int ngroups = (E + 63) >> 6;
    const int gstride = (int)gridDim.x * WPB;
    const int c_l  = lane & 15;
    const int k4   = lane >> 4;
    const int mcol = eperm(lane);                            // storage column
    const int drow = (c_l < DTROWS) ? c_l : (DTROWS - 1);    // junk -> discarded C cols
    int pg0 = 0, pg1 = 0;

    int grp = (int)blockIdx.x * WPB + wave;

    // 1-deep prefetch of the streaming loads (w, disp, idx) — no gathers
    float pw = 0.f, px = 0.f, py = 0.f, pz = 0.f;
    int   ps = 0, pt = 0;
    if (grp < ngroups) {
        int e  = grp * 64 + lane;
        int ec = e < E ? e : E - 1;
        pw = (e < E) ? edge_w[ec] : 0.f;   // w=0 kills clamped-tail terms
        px = disp[ec * 3 + 0];
        py = disp[ec * 3 + 1];
        pz = disp[ec * 3 + 2];
        ps = edge_index[ec];
        pt = edge_index[E + ec];
    }

    while (grp < ngroups) {
        const float w = pw, d0 = px, d1 = py, d2 = pz;
        const int   sC = ps, tC = pt;

        const int nxt = grp + gstride;
        if (nxt < ngroups) {
            int e  = nxt * 64 + lane;
            int ec = e < E ? e : E - 1;
            pw = (e < E) ? edge_w[ec] : 0.f;
            px = disp[ec * 3 + 0];
            py = disp[ec * 3 + 1];
            pz = disp[ec * 3 + 2];
            ps = edge_index[ec];
            pt = edge_index[E + ec];
        }

        // estimate-and-verify endpoint->graph (exact)
        const int g0 = gsearch(Bs, sC, rcpN);
        const int g1 = gsearch(Bs, tC, rcpN);

        // M one-hot (storage column mcol; plain stores, race-free)
        Mw[pg0 * MROWB + mcol] = 0;
        Mw[pg1 * MROWB + mcol] = 0;
        Mw[g0 * MROWB + mcol] = 0x38u;                         // e4m3 1.0
        Mw[g1 * MROWB + mcol] = (g1 == g0) ? 0x40u : 0x38u;    // e4m3 2.0/1.0
        pg0 = g0; pg1 = g1;

        float cw = -2.f * w;
        Dw[0 * DROWB + mcol] = f2fp8(cw * d0 * d0);
        Dw[1 * DROWB + mcol] = f2fp8(cw * d0 * d1);
        Dw[2 * DROWB + mcol] = f2fp8(cw * d0 * d2);
        Dw[3 * DROWB + mcol] = f2fp8(cw * d1 * d1);
        Dw[4 * DROWB + mcol] = f2fp8(cw * d1 * d2);
        Dw[5 * DROWB + mcol] = f2fp8(cw * d2 * d2);

        // fragments: one b128 per row covers BOTH K=32 chunks (R13-verified)
        long2_t bf = *(const long2_t*)&Dw[drow * DROWB + k4 * 16];
        long2_t a0 = *(const long2_t*)&Mw[( 0 + c_l) * MROWB + k4 * 16];
        long2_t a1 = *(const long2_t*)&Mw[(16 + c_l) * MROWB + k4 * 16];
        long2_t a2 = *(const long2_t*)&Mw[(32 + c_l) * MROWB + k4 * 16];
        long2_t a3 = *(const long2_t*)&Mw[(48 + c_l) * MROWB + k4 * 16];

        acc0 = __builtin_amdgcn_mfma_f32_16x16x32_fp8_fp8(a0[0], bf[0], acc0, 0, 0, 0);
        acc1 = __builtin_amdgcn_mfma_f32_16x16x32_fp8_fp8(a1[0], bf[0], acc1, 0, 0, 0);
        acc2 = __builtin_amdgcn_mfma_f32_16x16x32_fp8_fp8(a2[0], bf[0], acc2, 0, 0, 0);
        acc3 = __builtin_amdgcn_mfma_f32_16x16x32_fp8_fp8(a3[0], bf[0], acc3, 0, 0, 0);
        acc0 = __builtin_amdgcn_mfma_f32_16x16x32_fp8_fp8(a0[1], bf[1], acc0, 0, 0, 0);
        acc1 = __builtin_amdgcn_mfma_f32_16x16x32_fp8_fp8(a1[1], bf[1], acc1, 0, 0, 0);
        acc2 = __builtin_amdgcn_mfma_f32_16x16x32_fp8_fp8(a2[1], bf[1], acc2, 0, 0, 0);
        acc3 = __builtin_amdgcn_mfma_f32_16x16x32_fp8_fp8(a3[1], bf[1], acc3, 0, 0, 0);

        grp = nxt;
    }

    // C/D layout: col=lane&15, row=(lane>>4)*4+reg (dtype-independent).
    // Stage per-wave f32 partial into this wave's (now dead) M region.
    __syncthreads();
    float* Ow = (float*)Mw;   // 5120 B >= 1536 B needed
    if (c_l < NCOMP) {
#pragma unroll
        for (int r = 0; r < 4; ++r) {
            Ow[( 0 + k4 * 4 + r) * NCOMP + c_l] = acc0[r];
            Ow[(16 + k4 * 4 + r) * NCOMP + c_l] = acc1[r];
            Ow[(32 + k4 * 4 + r) * NCOMP + c_l] = acc2[r];
            Ow[(48 + k4 * 4 + r) * NCOMP + c_l] = acc3[r];
        }
    }
    __syncthreads();
    for (int i = threadIdx.x; i < NPART; i += blockDim.x) {
        float s = ((const float*)Msh[0])[i] + ((const float*)Msh[1])[i]
                + ((const float*)Msh[2])[i] + ((const float*)Msh[3])[i];
        partials[(size_t)blockIdx.x * NPART + i] = s;
    }
}

// ---------------- reductions (atomic-free; R22-verified) ----------------
__global__ __launch_bounds__(NPART) void reduce1_kernel(
    const float* __restrict__ partials, float* __restrict__ partials2, int nblk)
{
    int i = threadIdx.x, j = blockIdx.x;
    float s = 0.f;
    for (int b = j; b < nblk; b += RED1_BLOCKS)
        s += partials[(size_t)b * NPART + i];
    partials2[(size_t)j * NPART + i] = s;
}

__global__ __launch_bounds__(NPART) void reduce2_kernel(
    const float* __restrict__ partials2, float* __restrict__ dst)  // dst: 64*9
{
    int i = threadIdx.x;
    float s = 0.f;
#pragma unroll
    for (int j = 0; j < RED1_BLOCKS; ++j)
        s += partials2[(size_t)j * NPART + i];
    int g = i / NCOMP, c = i % NCOMP;
    int r   = (c < 3) ? 0 : ((c < 5) ? 1 : 2);
    int col = (c < 3) ? c : ((c < 5) ? c - 2 : 2);
    dst[g * 9 + r * 3 + col] = s;
    if (r != col) dst[g * 9 + col * 3 + r] = s;
}

// ---------------- fallback (tiny ws): LDS-atomic path ----------------
__global__ void zero_out_kernel(float* __restrict__ out, int n) {
    int i = blockIdx.x * blockDim.x + threadIdx.x;
    if (i < n) out[i] = 0.f;
}

__global__ __launch_bounds__(256) void virial_atomic(
    const float* __restrict__ disp, const float* __restrict__ edge_w,
    const int* __restrict__ edge_index, const int* __restrict__ batch,
    float* __restrict__ out, int E)
{
    __shared__ float acc[NG * 7];
    for (int i = threadIdx.x; i < NG * 7; i += blockDim.x) acc[i] = 0.f;
    __syncthreads();
    int tid = blockIdx.x * blockDim.x + threadIdx.x;
    int stride = gridDim.x * blockDim.x;
    for (int e = tid; e < E; e += stride) {
        float d0 = disp[e*3], d1 = disp[e*3+1], d2 = disp[e*3+2];
        float c = -2.f * edge_w[e];
        int g0 = batch[edge_index[e]], g1 = batch[edge_index[E + e]];
        float v[6] = {c*d0*d0, c*d0*d1, c*d0*d2, c*d1*d1, c*d1*d2, c*d2*d2};
#pragma unroll
        for (int k = 0; k < 6; ++k) {
            lds_add(&acc[g0*7+k], v[k]);
            lds_add(&acc[g1*7+k], v[k]);
        }
    }
    __syncthreads();
    for (int i = threadIdx.x; i < NG * 9; i += blockDim.x) {
        int g = i / 9, ij = i % 9, r = ij / 3, cc = ij % 3;
        int lo = r < cc ? r : cc, hi = r < cc ? cc : r;
        int comp = (lo == 0) ? hi : ((lo == 1) ? 2 + hi : 5);
        __hip_atomic_fetch_add(&out[i], acc[g*7+comp], __ATOMIC_RELAXED, __HIP_MEMORY_SCOPE_AGENT);
    }
}

extern "C" void kernel_launch(void* const* d_in, const int* in_sizes, int n_in,
                              void* d_out, int out_size, void* d_ws, size_t ws_size,
                              hipStream_t stream) {
    const float* disp       = (const float*)d_in[0];
    const float* edge_w     = (const float*)d_in[1];
    const int*   edge_index = (const int*)d_in[2];
    const int*   batch      = (const int*)d_in[3];
    float*       out        = (float*)d_out;
    const int E = in_sizes[1];
    const int N = in_sizes[3];
    const float rcpN = (float)NG / (float)N;

    const size_t need = (size_t)(MFMA_BLOCKS + RED1_BLOCKS) * NPART * sizeof(float);

    if (ws_size >= need) {
        float* pm = (float*)d_ws;                         // [MFMA_BLOCKS][NPART]
        float* p2 = pm + (size_t)MFMA_BLOCKS * NPART;     // [RED1_BLOCKS][NPART]

        virial_mfma<<<MFMA_BLOCKS, 256, 0, stream>>>(disp, edge_w, edge_index,
                                                     batch, pm, E, N, rcpN);
        reduce1_kernel<<<RED1_BLOCKS, NPART, 0, stream>>>(pm, p2, MFMA_BLOCKS);
        reduce2_kernel<<<1, NPART, 0, stream>>>(p2, out);
    } else {
        zero_out_kernel<<<1, 256, 0, stream>>>(out, NG * 9);
        virial_atomic<<<2048, 256, 0, stream>>>(disp, edge_w, edge_index, batch, out, E);
    }
}